// Round 5
// baseline (528.146 us; speedup 1.0000x reference)
//
#include <hip/hip_runtime.h>

// Problem constants (match reference setup_inputs)
#define B    64
#define OBJS 2048
#define NTOT (B * OBJS)       // 131072
#define D    256
#define K    2

// Fused persistent kernel geometry.
// CO-RESIDENCY INVARIANT (deadlock-free scene barrier):
//   grid = 512 blocks = 2 blocks/CU x 256 CUs. Guaranteed by
//   __launch_bounds__(256,2) (VGPR <= 256 -> 2 waves/SIMD) and
//   LDS/block ~= 77 KiB <= 160/2 KiB. All blocks co-resident -> spin is safe.
#define SPB   8               // blocks per scene
#define GRID  (B * SPB)       // 512
#define RPB   (OBJS / SPB)    // 256 rows per block
#define RPWV  (RPB / 4)       // 64 rows per wave
#define NREG  45              // rows kept in registers per wave (180 VGPRs)
#define NLDS  19              // rows kept in LDS per wave (19*1KiB*4 waves = 76 KiB)

// Workspace layout (float offsets)
#define WS_P1  0                          // GRID*4*256 per-wave colsum partials
#define WS_UP  (GRID * 4 * 256)           // GRID*512   per-block U partials
#define WS_ZP  (WS_UP + GRID * 512)       // GRID*2     per-block Z partials
#define WS_CNT (WS_ZP + GRID * 2)         // 128 ints: cnt1[64], cnt2[64]

static __device__ __forceinline__ float lrelu02(float v) {
    return v > 0.0f ? v : 0.2f * v;
}

static __device__ __forceinline__ float ldg_agent(const float* p) {
    return __hip_atomic_load(p, __ATOMIC_RELAXED, __HIP_MEMORY_SCOPE_AGENT);
}

// device-scope scene barrier: publish prior stores, count in, spin to `expect`
static __device__ __forceinline__ void scene_barrier(int* cnt, int expect) {
    __builtin_amdgcn_fence(__ATOMIC_RELEASE, "agent");
    __syncthreads();
    if (threadIdx.x == 0) {
        __hip_atomic_fetch_add(cnt, 1, __ATOMIC_ACQ_REL, __HIP_MEMORY_SCOPE_AGENT);
        int it = 0;
        while (__hip_atomic_load(cnt, __ATOMIC_ACQUIRE, __HIP_MEMORY_SCOPE_AGENT) < expect) {
            __builtin_amdgcn_s_sleep(2);
            if (++it > (1 << 26)) break;   // anti-hang valve (wrong > hung)
        }
    }
    __syncthreads();
    __builtin_amdgcn_fence(__ATOMIC_ACQUIRE, "agent");
}

// per-row body of pass 2: dot -> broadcast -> exp -> accumulate
#define ROW_BODY(JCONST, V)                                                   \
    {                                                                         \
        float p = lrelu02((V).x + ctx4.x) * a4.x                              \
                + lrelu02((V).y + ctx4.y) * a4.y                              \
                + lrelu02((V).z + ctx4.z) * a4.z                              \
                + lrelu02((V).w + ctx4.w) * a4.w;                             \
        _Pragma("unroll")                                                     \
        for (int m_ = 32; m_ > 0; m_ >>= 1) p += __shfl_xor(p, m_);           \
        float e0_ = __expf((p + bt0) * s0);                                   \
        float e1_ = __expf((p + bt1) * s1);                                   \
        if ((JCONST) == l) { e0c = e0_; e1c = e1_; }                          \
        acc0.x += (V).x * e0_; acc0.y += (V).y * e0_;                         \
        acc0.z += (V).z * e0_; acc0.w += (V).w * e0_;                         \
        acc1.x += (V).x * e1_; acc1.y += (V).y * e1_;                         \
        acc1.z += (V).z * e1_; acc1.w += (V).w * e1_;                         \
        z0 += e0_; z1 += e1_;                                                 \
    }

__global__ __launch_bounds__(256, 2)
void fused_kernel(const float* __restrict__ x,
                  const int* __restrict__ num_objs,
                  const float* __restrict__ att_scale,
                  const float* __restrict__ att_shared,
                  const float* __restrict__ channel_bias,
                  float* __restrict__ ws,
                  float* __restrict__ out) {
    __shared__ float xlds[4 * NLDS * D];   // 76 KiB: 19 rows/wave x 4 waves
    __shared__ float sctx[D];              // scene ctx mean
    __shared__ float sbt[2];               // bias_term per channel
    __shared__ float zsh[8];               // per-wave Z partials

    int blk = blockIdx.x;
    int b = blk >> 3, c = blk & 7;
    int t = threadIdx.x;
    int w = t >> 6, l = t & 63;
    int* cnt1 = (int*)(ws + WS_CNT) + b;
    int* cnt2 = (int*)(ws + WS_CNT) + 64 + b;

    // ---- phase A: load this block's 256 rows once; column-sum on the fly ----
    // wave w owns rows [blk*256 + w*64, +64): 45 rows -> registers, 19 -> LDS
    const float4* px = (const float4*)x + (size_t)(blk * RPB + w * RPWV) * (D / 4) + l;
    float4 xr[NREG];
    float4 csum = make_float4(0.f, 0.f, 0.f, 0.f);
#pragma unroll
    for (int j = 0; j < NREG; ++j) {
        float4 v = px[(size_t)j * (D / 4)];
        xr[j] = v;
        csum.x += v.x; csum.y += v.y; csum.z += v.z; csum.w += v.w;
    }
#pragma unroll
    for (int j = NREG; j < RPWV; ++j) {
        float4 v = px[(size_t)j * (D / 4)];
        csum.x += v.x; csum.y += v.y; csum.z += v.z; csum.w += v.w;
        *(float4*)&xlds[(w * NLDS + (j - NREG)) * D + 4 * l] = v;
    }
    // per-wave colsum partial -> ws (coalesced 1 KiB per wave)
    *(float4*)&ws[WS_P1 + (size_t)(blk * 4 + w) * D + 4 * l] = csum;

    // bias_term (wave 0, overlaps with other waves' stores)
    if (t < 64) {
        float4 a = ((const float4*)att_shared)[t];
#pragma unroll
        for (int k = 0; k < K; ++k) {
            float4 cb = ((const float4*)(channel_bias + k * D))[t];
            float v = a.x * cb.x + a.y * cb.y + a.z * cb.z + a.w * cb.w;
#pragma unroll
            for (int m = 32; m > 0; m >>= 1) v += __shfl_xor(v, m);
            if (t == 0) sbt[k] = v;
        }
    }

    // ---- scene barrier 1: all 8 blocks' colsum partials published ----
    scene_barrier(cnt1, SPB);

    // ---- ctx mean: thread t reduces column t over the scene's 32 partials ----
    {
        int cntv = num_objs[b]; if (cntv < 1) cntv = 1;
        float inv = 1.0f / (float)cntv;
        float s = 0.f;
#pragma unroll
        for (int cc = 0; cc < SPB; ++cc)
#pragma unroll
            for (int ww = 0; ww < 4; ++ww)
                s += ldg_agent(&ws[WS_P1 + (size_t)((b * SPB + cc) * 4 + ww) * D + t]);
        sctx[t] = s * inv;
    }
    __syncthreads();

    // ---- phase B: pass 2 entirely from registers/LDS (zero HBM re-read) ----
    float4 a4   = ((const float4*)att_shared)[l];
    float4 ctx4 = *(const float4*)(sctx + 4 * l);
    float bt0 = sbt[0], bt1 = sbt[1];
    float s0 = att_scale[0], s1 = att_scale[1];

    float4 acc0 = make_float4(0.f, 0.f, 0.f, 0.f);
    float4 acc1 = make_float4(0.f, 0.f, 0.f, 0.f);
    float z0 = 0.f, z1 = 0.f;
    float e0c = 0.f, e1c = 0.f;   // lane l captures row (row0w + l)'s exps

#pragma unroll
    for (int j = 0; j < NREG; ++j) ROW_BODY(j, xr[j]);
#pragma unroll
    for (int j = NREG; j < RPWV; ++j) {
        float4 v = *(const float4*)&xlds[(w * NLDS + (j - NREG)) * D + 4 * l];
        ROW_BODY(j, v);
    }

    // ---- block-level U/Z reduce (xlds reusable after barrier) ----
    __syncthreads();   // x in LDS fully consumed by all waves
    if (l == 0) { zsh[w * 2] = z0; zsh[w * 2 + 1] = z1; }
    {
        int base = w * (D * K) + l * 8;   // col (4l+m)*2+k within wave region
        xlds[base + 0] = acc0.x; xlds[base + 1] = acc1.x;
        xlds[base + 2] = acc0.y; xlds[base + 3] = acc1.y;
        xlds[base + 4] = acc0.z; xlds[base + 5] = acc1.z;
        xlds[base + 6] = acc0.w; xlds[base + 7] = acc1.w;
    }
    __syncthreads();
    if (t < 128) {
        float4 a = ((const float4*)(xlds       ))[t];
        float4 e = ((const float4*)(xlds +  512))[t];
        float4 f = ((const float4*)(xlds + 1024))[t];
        float4 g = ((const float4*)(xlds + 1536))[t];
        float4 s4 = make_float4(a.x + e.x + f.x + g.x, a.y + e.y + f.y + g.y,
                                a.z + e.z + f.z + g.z, a.w + e.w + f.w + g.w);
        *(float4*)&ws[WS_UP + (size_t)blk * (D * K) + 4 * t] = s4;
    }
    if (t == 0) {
        ws[WS_ZP + blk * 2 + 0] = zsh[0] + zsh[2] + zsh[4] + zsh[6];
        ws[WS_ZP + blk * 2 + 1] = zsh[1] + zsh[3] + zsh[5] + zsh[7];
    }

    // ---- scene barrier 2: all 8 blocks' U/Z partials published ----
    scene_barrier(cnt2, SPB);

    // scene totals Z
    float z0T = 0.f, z1T = 0.f;
#pragma unroll
    for (int cc = 0; cc < SPB; ++cc) {
        z0T += ldg_agent(&ws[WS_ZP + (b * SPB + cc) * 2 + 0]);
        z1T += ldg_agent(&ws[WS_ZP + (b * SPB + cc) * 2 + 1]);
    }

    // attn weights for this block's rows (lane l owns row row0w + l)
    {
        float2* W = (float2*)(out + B * D * K);
        int row = blk * RPB + w * RPWV + l;
        W[row] = make_float2(e0c / z0T, e1c / z1T);
    }

    // scene features: block c==0 of each scene reduces the 8 U partials
    if (c == 0) {
#pragma unroll
        for (int rep = 0; rep < 2; ++rep) {
            int j = t + rep * 256;        // j = d*2+k in [0,512)
            float s = 0.f;
#pragma unroll
            for (int cc = 0; cc < SPB; ++cc)
                s += ldg_agent(&ws[WS_UP + (size_t)(b * SPB + cc) * (D * K) + j]);
            out[b * (D * K) + j] = s / ((j & 1) ? z1T : z0T);
        }
    }
}

extern "C" void kernel_launch(void* const* d_in, const int* in_sizes, int n_in,
                              void* d_out, int out_size, void* d_ws, size_t ws_size,
                              hipStream_t stream) {
    const float* x            = (const float*)d_in[0];   // [N, D]
    const int*   num_objs     = (const int*)d_in[1];     // [B]
    const float* att_shared   = (const float*)d_in[2];   // [1, D]
    const float* att_scale    = (const float*)d_in[3];   // [K, 1]
    const float* channel_bias = (const float*)d_in[4];   // [K, D]
    float* ws  = (float*)d_ws;
    float* out = (float*)d_out;

    // zero only the barrier counters (ws is poisoned 0xAA each replay)
    (void)hipMemsetAsync((char*)d_ws + (size_t)WS_CNT * sizeof(float), 0,
                         128 * sizeof(int), stream);

    fused_kernel<<<GRID, 256, 0, stream>>>(x, num_objs, att_scale, att_shared,
                                           channel_bias, ws, out);
}

// Round 7
// 222.673 us; speedup vs baseline: 2.3718x; 2.3718x over previous
//
#include <hip/hip_runtime.h>

// Problem constants (match reference setup_inputs)
#define B    64
#define OBJS 2048
#define NTOT (B * OBJS)       // 131072
#define D    256
#define K    2
#define S1   16               // blocks per scene for heavy passes
#define CH   (OBJS / S1)      // 128 rows per block
#define RPW  (CH / 4)         // 32 rows per wave (contiguous chunk)

// Workspace layout (floats); ws is far larger than needed.
#define WS_P1  0                          // 1024 * 256  k1 partial ctx sums
#define WS_UP  (1024 * 256)               // 1024 * 512  k2 partial U
#define WS_ZP  (WS_UP + 1024 * 512)       // 1024 * 8    k2 partial Z
#define WS_E   (WS_ZP + 1024 * 8)         // NTOT * 2    exp(logit) per row (16B aligned)

static __device__ __forceinline__ float lrelu02(float v) {
    return v > 0.0f ? v : 0.2f * v;
}

// ---- pass 1: per-block partial column sums of x (streams 128 MiB from HBM) ----
__global__ __launch_bounds__(256) void k1_partial(const float* __restrict__ x,
                                                  float* __restrict__ ws) {
    __shared__ float red[4 * D];
    int blk = blockIdx.x;
    int w = threadIdx.x >> 6, l = threadIdx.x & 63;
    int row0 = blk * CH + w * RPW;

    float4 acc = make_float4(0.f, 0.f, 0.f, 0.f);
    const float* px = x + (size_t)row0 * D + 4 * l;
#pragma unroll 8
    for (int j = 0; j < RPW; ++j) {
        float4 v = *(const float4*)(px + (size_t)j * D);
        acc.x += v.x; acc.y += v.y; acc.z += v.z; acc.w += v.w;
    }
    *(float4*)(red + w * D + 4 * l) = acc;
    __syncthreads();
    int t = threadIdx.x;
    if (t < 64) {
        float4 a = ((const float4*)(red        ))[t];
        float4 e = ((const float4*)(red +     D))[t];
        float4 f = ((const float4*)(red + 2 * D))[t];
        float4 g = ((const float4*)(red + 3 * D))[t];
        float4 s = make_float4(a.x + e.x + f.x + g.x, a.y + e.y + f.y + g.y,
                               a.z + e.z + f.z + g.z, a.w + e.w + f.w + g.w);
        *(float4*)(ws + WS_P1 + blk * D + 4 * t) = s;
    }
}

// ---- pass 2: batch-8 LDS-transpose reduction (no per-row butterfly) ----
__global__ __launch_bounds__(256) void k2_main(const float* __restrict__ x,
                                               const int* __restrict__ num_objs,
                                               const float* __restrict__ att_scale,
                                               const float* __restrict__ att_shared,
                                               const float* __restrict__ channel_bias,
                                               float* __restrict__ ws) {
    // pl: 4 waves * 64 lanes * stride 9 (conflict-free transpose buffer); reused as ured
    __shared__ float pl[4 * 576];       // 9216 B
    __shared__ float esm[4 * 16];       // per-wave e broadcast (8 rows x (e0,e1))
    __shared__ float sctx[D];
    __shared__ float sbt[2];

    int blk = blockIdx.x;
    int b = blk >> 4;
    int t = threadIdx.x;
    int w = t >> 6, l = t & 63;
    int r = l & 7, s = l >> 3;
    int row0 = blk * CH + w * RPW;      // contiguous 32-row chunk per wave

    // prologue A: reduce this scene's 16 ctx partials (16 KB, L2/L3-hit)
    {
        int cnt = num_objs[b]; if (cnt < 1) cnt = 1;
        float inv = 1.0f / (float)cnt;
        float sum = 0.f;
#pragma unroll
        for (int c = 0; c < S1; ++c) sum += ws[WS_P1 + (b * S1 + c) * D + t];
        sctx[t] = sum * inv;
    }
    // prologue B: bias_term[k] = channel_bias[k,:] . att_shared (wave 0)
    if (t < 64) {
        float4 a = ((const float4*)att_shared)[t];
#pragma unroll
        for (int k = 0; k < K; ++k) {
            float4 cb = ((const float4*)(channel_bias + k * D))[t];
            float v = a.x * cb.x + a.y * cb.y + a.z * cb.z + a.w * cb.w;
#pragma unroll
            for (int m = 32; m > 0; m >>= 1) v += __shfl_xor(v, m);
            if (t == 0) sbt[k] = v;
        }
    }
    __syncthreads();

    float4 a4   = ((const float4*)att_shared)[l];
    float4 ctx4 = *(const float4*)(sctx + 4 * l);
    float bt0 = sbt[0], bt1 = sbt[1];
    float s0 = att_scale[0], s1 = att_scale[1];

    float4 acc0 = make_float4(0.f, 0.f, 0.f, 0.f);
    float4 acc1 = make_float4(0.f, 0.f, 0.f, 0.f);
    float z0 = 0.f, z1 = 0.f;
    float e0c = 0.f, e1c = 0.f;            // lane l<32 captures row (row0 + l)'s exps
    float* pw = pl  + w * 576;
    float* ew = esm + w * 16;
    const float* px = x + (size_t)row0 * D + 4 * l;

#pragma unroll
    for (int g = 0; g < 4; ++g) {
        float4 v0 = *(const float4*)(px + (size_t)(g * 8 + 0) * D);
        float4 v1 = *(const float4*)(px + (size_t)(g * 8 + 1) * D);
        float4 v2 = *(const float4*)(px + (size_t)(g * 8 + 2) * D);
        float4 v3 = *(const float4*)(px + (size_t)(g * 8 + 3) * D);
        float4 v4 = *(const float4*)(px + (size_t)(g * 8 + 4) * D);
        float4 v5 = *(const float4*)(px + (size_t)(g * 8 + 5) * D);
        float4 v6 = *(const float4*)(px + (size_t)(g * 8 + 6) * D);
        float4 v7 = *(const float4*)(px + (size_t)(g * 8 + 7) * D);

#define PDOT(V) (lrelu02((V).x + ctx4.x) * a4.x + lrelu02((V).y + ctx4.y) * a4.y \
               + lrelu02((V).z + ctx4.z) * a4.z + lrelu02((V).w + ctx4.w) * a4.w)
        // per-lane partial dots -> LDS (stride-9: conflict-free)
        pw[l * 9 + 0] = PDOT(v0); pw[l * 9 + 1] = PDOT(v1);
        pw[l * 9 + 2] = PDOT(v2); pw[l * 9 + 3] = PDOT(v3);
        pw[l * 9 + 4] = PDOT(v4); pw[l * 9 + 5] = PDOT(v5);
        pw[l * 9 + 6] = PDOT(v6); pw[l * 9 + 7] = PDOT(v7);
#undef PDOT
        // lane (r,s) sums orig-lanes 8s..8s+7 for row r (2-way bank alias: free)
        float tr = 0.f;
#pragma unroll
        for (int q = 0; q < 8; ++q) tr += pw[(s * 8 + q) * 9 + r];
        tr += __shfl_xor(tr, 8);
        tr += __shfl_xor(tr, 16);
        tr += __shfl_xor(tr, 32);      // all lanes now hold base of row g*8 + (l&7)

        float e0 = __expf((tr + bt0) * s0);
        float e1 = __expf((tr + bt1) * s1);
        // lane l (l<32) owns row row0+l = row0 + ((l>>3)&3)*8 + (l&7)
        if (((l >> 3) & 3) == g) { e0c = e0; e1c = e1; }
        if (l < 8) { ew[2 * l] = e0; ew[2 * l + 1] = e1; }
        float4 E0 = *(const float4*)(ew + 0);   // (e0[0],e1[0],e0[1],e1[1])
        float4 E1 = *(const float4*)(ew + 4);
        float4 E2 = *(const float4*)(ew + 8);
        float4 E3 = *(const float4*)(ew + 12);
        z0 += E0.x + E0.z + E1.x + E1.z + E2.x + E2.z + E3.x + E3.z;
        z1 += E0.y + E0.w + E1.y + E1.w + E2.y + E2.w + E3.y + E3.w;

#define ACC(V, EA, EB) { acc0.x += (V).x * (EA); acc0.y += (V).y * (EA);      \
                         acc0.z += (V).z * (EA); acc0.w += (V).w * (EA);      \
                         acc1.x += (V).x * (EB); acc1.y += (V).y * (EB);      \
                         acc1.z += (V).z * (EB); acc1.w += (V).w * (EB); }
        ACC(v0, E0.x, E0.y) ACC(v1, E0.z, E0.w)
        ACC(v2, E1.x, E1.y) ACC(v3, E1.z, E1.w)
        ACC(v4, E2.x, E2.y) ACC(v5, E2.z, E2.w)
        ACC(v6, E3.x, E3.y) ACC(v7, E3.z, E3.w)
#undef ACC
    }

    // e store: lane l (l<32) owns row row0 + l (coalesced float2) — lanes 32..63
    // hold duplicates of rows owned by the NEXT wave's chunk and must NOT store.
    if (l < 32) ((float2*)(ws + WS_E))[row0 + l] = make_float2(e0c, e1c);
    // per-wave Z partial
    if (l == 0) {
        ws[WS_ZP + blk * 8 + w * 2 + 0] = z0;
        ws[WS_ZP + blk * 8 + w * 2 + 1] = z1;
    }
    // cross-wave U reduce in LDS (reuse pl), one coalesced 2 KB store per block
    __syncthreads();
    {
        int base = w * (D * K) + l * 8;   // col (4l+m)*2+k within wave region
        pl[base + 0] = acc0.x; pl[base + 1] = acc1.x;
        pl[base + 2] = acc0.y; pl[base + 3] = acc1.y;
        pl[base + 4] = acc0.z; pl[base + 5] = acc1.z;
        pl[base + 6] = acc0.w; pl[base + 7] = acc1.w;
    }
    __syncthreads();
    if (t < 128) {
        float4 a = ((const float4*)(pl       ))[t];
        float4 e = ((const float4*)(pl +  512))[t];
        float4 f = ((const float4*)(pl + 1024))[t];
        float4 g = ((const float4*)(pl + 1536))[t];
        float4 s4 = make_float4(a.x + e.x + f.x + g.x, a.y + e.y + f.y + g.y,
                                a.z + e.z + f.z + g.z, a.w + e.w + f.w + g.w);
        *(float4*)(ws + WS_UP + (size_t)blk * (D * K) + 4 * t) = s4;
    }
}

// ---- finalize, one block per scene: reduce Z/U, write features + weights ----
__global__ __launch_bounds__(256) void k3_final(const float* __restrict__ ws,
                                                float* __restrict__ out) {
    __shared__ float zsh[2];
    int b = blockIdx.x;
    int t = threadIdx.x;
    int w = t >> 6, l = t & 63;

    // waves 0/1 reduce Z for channel 0/1: 64 partials each (16 blocks x 4 waves)
    if (w < 2) {
        float v = ws[WS_ZP + (b * S1 + (l >> 2)) * 8 + (l & 3) * 2 + w];
#pragma unroll
        for (int m = 32; m > 0; m >>= 1) v += __shfl_xor(v, m);
        if (l == 0) zsh[w] = v;
    }
    __syncthreads();
    float z0 = zsh[0], z1 = zsh[1];
    float iz0 = 1.0f / z0, iz1 = 1.0f / z1;

    // features: out[b*512 + j], j = d*2+k
#pragma unroll
    for (int j = t; j < D * K; j += 256) {
        float s = 0.f;
#pragma unroll
        for (int c = 0; c < S1; ++c) s += ws[WS_UP + (b * S1 + c) * (D * K) + j];
        out[b * (D * K) + j] = s * ((j & 1) ? iz1 : iz0);
    }
    // weights: float4 = 2 rows at a time
    const float4* E = (const float4*)(ws + WS_E);
    float4* W = (float4*)(out + B * D * K);
#pragma unroll
    for (int i = t; i < OBJS / 2; i += 256) {
        float4 e = E[b * (OBJS / 2) + i];
        W[b * (OBJS / 2) + i] = make_float4(e.x * iz0, e.y * iz1, e.z * iz0, e.w * iz1);
    }
}

extern "C" void kernel_launch(void* const* d_in, const int* in_sizes, int n_in,
                              void* d_out, int out_size, void* d_ws, size_t ws_size,
                              hipStream_t stream) {
    const float* x            = (const float*)d_in[0];   // [N, D]
    const int*   num_objs     = (const int*)d_in[1];     // [B]
    const float* att_shared   = (const float*)d_in[2];   // [1, D]
    const float* att_scale    = (const float*)d_in[3];   // [K, 1]
    const float* channel_bias = (const float*)d_in[4];   // [K, D]
    float* ws  = (float*)d_ws;
    float* out = (float*)d_out;

    // no memset needed: every ws/out location is written before it is read
    k1_partial<<<B * S1, 256, 0, stream>>>(x, ws);
    k2_main<<<B * S1, 256, 0, stream>>>(x, num_objs, att_scale, att_shared,
                                        channel_bias, ws);
    k3_final<<<B, 256, 0, stream>>>(ws, out);
}